// Round 10
// baseline (299.744 us; speedup 1.0000x reference)
//
#include <hip/hip_runtime.h>
#include <hip/hip_bf16.h>
#include <math.h>

#define HWP 1024
#define NHEAD 8
#define NBLK 512

typedef __attribute__((ext_vector_type(8))) short s8v;
typedef __attribute__((ext_vector_type(4))) float f32x4;

#define WB_N   1179648   // 1024*1152
#define XT_N   591872    // 4*34*34*128
#define WAB_N  65536
#define KRB_N  4096
#define TOT_PREP (WB_N + XT_N + WAB_N + KRB_N)

// Device-scope grid barrier: all 512 blocks are co-resident (2 blocks/CU
// guaranteed by launch_bounds + 48KB LDS), so spinning is deadlock-free.
// atomicAdd(global) is device-scope; __threadfence() is the device fence
// (L2 writeback + invalidate) needed for cross-XCD visibility.
__device__ __forceinline__ void grid_barrier(unsigned* cnt) {
    __syncthreads();
    if (threadIdx.x == 0) {
        __threadfence();
        atomicAdd(cnt, 1u);
        while (atomicAdd(cnt, 0u) < NBLK) __builtin_amdgcn_s_sleep(2);
        __threadfence();
    }
    __syncthreads();
}

__global__ __launch_bounds__(256, 2) void mega_kernel(
    const float* __restrict__ x,
    const float* __restrict__ conv_w, const float* __restrict__ conv_b,
    const float* __restrict__ qkv_w, const float* __restrict__ qkv_b,
    const float* __restrict__ att_w, const float* __restrict__ att_b,
    const float* __restrict__ kr_x, const float* __restrict__ kr_y,
    float* __restrict__ out,
    __hip_bfloat16* __restrict__ qbf, __hip_bfloat16* __restrict__ kbf,
    __hip_bfloat16* __restrict__ vtb, __hip_bfloat16* __restrict__ xT,
    __hip_bfloat16* __restrict__ Wb, __hip_bfloat16* __restrict__ Wab,
    __hip_bfloat16* __restrict__ krb, __hip_bfloat16* __restrict__ attc,
    unsigned* __restrict__ bar)
{
    __shared__ __align__(16) char smem[49152];

    const int bid = blockIdx.x;
    const int tid = threadIdx.x;
    const int wv = tid >> 6;
    const int lane = tid & 63;
    const int n16 = lane & 15;
    const int quad = lane >> 4;

    // ================= Phase 0: prep (grid-stride) =================
    {
        for (int g = bid * 256 + tid; g < TOT_PREP; g += NBLK * 256) {
            if (g < WB_N) {
                int co = g / 1152;
                int k = g - co * 1152;
                int kk = k >> 7, ci = k & 127;
                float v;
                if (co < 256) v = conv_w[((size_t)(co * 128 + ci) * 9) + kk];
                else          v = qkv_w[((size_t)((co - 256) * 128 + ci) * 9) + kk];
                Wb[(size_t)co * 1152 + k] = __float2bfloat16(v);
            } else if (g < WB_N + XT_N) {
                int rel = g - WB_N;
                int ci = rel & 127;
                int t = rel >> 7;          // (b*34+yy)*34+xx
                int xx = t % 34;
                int t2 = t / 34;
                int yy = t2 % 34;
                int b = t2 / 34;
                float v = 0.f;
                int gy = yy - 1, gx = xx - 1;
                if ((unsigned)gy < 32u && (unsigned)gx < 32u)
                    v = x[((size_t)(b * 128 + ci) * 32 + gy) * 32 + gx];
                xT[(size_t)rel] = __float2bfloat16(v);
            } else if (g < WB_N + XT_N + WAB_N) {
                int rel = g - (WB_N + XT_N);
                Wab[rel] = __float2bfloat16(att_w[rel]);
            } else {
                int rel = g - (WB_N + XT_N + WAB_N);
                int col = (rel >> 5) & 63;
                int d = rel & 31;
                int axis = rel >> 11;
                float v = 0.f;
                if (col < 63) v = axis ? kr_y[col * 32 + d] : kr_x[col * 32 + d];
                krb[rel] = __float2bfloat16(v);
            }
        }
    }
    grid_barrier(&bar[0]);

    // ================= Phase 1: 3x3 conv implicit-GEMM (128co x 64pix) ======
    {
        __hip_bfloat16* As = (__hip_bfloat16*)smem;             // 128x128
        __hip_bfloat16* Bs = (__hip_bfloat16*)(smem + 32768);   // 64x128
        const int ph = bid & 1;
        const int b = (bid >> 1) & 3;
        const int yt = (bid >> 3) & 7;
        const int ct = bid >> 6;
        const int co0 = ct * 128;
        const int pixBase = yt * 128 + ph * 64;
        const int row0 = pixBase >> 5;
        const int mh = wv >> 1, nh = wv & 1;
        const int rbase = tid >> 4;
        const int hh = tid & 15;
        const int swz = (hh ^ rbase) * 8;
        const __hip_bfloat16* aGbase = Wb + (size_t)(co0 + rbase) * 1152 + hh * 8;

        f32x4 acc[4][2];
#pragma unroll
        for (int i = 0; i < 4; ++i)
#pragma unroll
            for (int j = 0; j < 2; ++j) acc[i][j] = (f32x4){0.f, 0.f, 0.f, 0.f};

        s8v ra[8], rb2[4];
        auto load_tile = [&](int kk, s8v* la, s8v* lb) {
            const int ky = kk / 3, kx = kk - ky * 3;
#pragma unroll
            for (int i = 0; i < 8; ++i)
                la[i] = *reinterpret_cast<const s8v*>(aGbase + (size_t)(16 * i) * 1152 + kk * 128);
#pragma unroll
            for (int i = 0; i < 4; ++i) {
                int p = rbase + 16 * i;
                lb[i] = *reinterpret_cast<const s8v*>(
                    xT + ((size_t)(b * 34 + row0 + (p >> 5) + ky) * 34 + (p & 31) + kx) * 128 + hh * 8);
            }
        };

        load_tile(0, ra, rb2);

        for (int s = 0; s < 9; ++s) {
            __syncthreads();
#pragma unroll
            for (int i = 0; i < 8; ++i)
                *reinterpret_cast<s8v*>(&As[(rbase + 16 * i) * 128 + swz]) = ra[i];
#pragma unroll
            for (int i = 0; i < 4; ++i)
                *reinterpret_cast<s8v*>(&Bs[(rbase + 16 * i) * 128 + swz]) = rb2[i];
            __syncthreads();
            if (s < 8) load_tile(s + 1, ra, rb2);

#pragma unroll
            for (int ksub = 0; ksub < 4; ++ksub) {
                const int chunk = ((ksub * 4 + quad) ^ n16) * 8;
                s8v af[4], bfr[2];
#pragma unroll
                for (int mt = 0; mt < 4; ++mt)
                    af[mt] = *reinterpret_cast<const s8v*>(&As[(mh * 64 + mt * 16 + n16) * 128 + chunk]);
#pragma unroll
                for (int nt = 0; nt < 2; ++nt)
                    bfr[nt] = *reinterpret_cast<const s8v*>(&Bs[(nh * 32 + nt * 16 + n16) * 128 + chunk]);
#pragma unroll
                for (int mt = 0; mt < 4; ++mt)
#pragma unroll
                    for (int nt = 0; nt < 2; ++nt)
                        acc[mt][nt] = __builtin_amdgcn_mfma_f32_16x16x32_bf16(af[mt], bfr[nt], acc[mt][nt], 0, 0, 0);
            }
        }

        const int coBase = co0 + mh * 64;
        const int pixW = pixBase + nh * 32;
        const int seg = coBase >> 8;

        if (seg == 0) {
#pragma unroll
            for (int mt = 0; mt < 4; ++mt)
#pragma unroll
                for (int r = 0; r < 4; ++r) {
                    int co = coBase + mt * 16 + quad * 4 + r;
                    float bias = conv_b[co];
                    float* op = out + (size_t)(b * 512 + co) * HWP + pixW;
#pragma unroll
                    for (int nt = 0; nt < 2; ++nt)
                        op[nt * 16 + n16] = acc[mt][nt][r] + bias;
                }
        } else if (seg == 1) {
            const float scale = 0.17677669529663687f;
#pragma unroll
            for (int mt = 0; mt < 4; ++mt)
#pragma unroll
                for (int r = 0; r < 4; ++r) {
                    int c2 = coBase - 256 + mt * 16 + quad * 4 + r;
                    float bias = qkv_b[c2];
                    int h = c2 >> 5, d = c2 & 31;
                    int bh = b * NHEAD + h;
#pragma unroll
                    for (int nt = 0; nt < 2; ++nt) {
                        int pix = pixW + nt * 16 + n16;
                        qbf[((size_t)bh * HWP + pix) * 32 + d] =
                            __float2bfloat16((acc[mt][nt][r] + bias) * scale);
                    }
                }
        } else if (seg == 2) {
#pragma unroll
            for (int mt = 0; mt < 4; ++mt)
#pragma unroll
                for (int r = 0; r < 4; ++r) {
                    int c2 = coBase - 512 + mt * 16 + quad * 4 + r;
                    float bias = qkv_b[c2 + 256];
                    int h = c2 >> 5, d = c2 & 31;
                    int bh = b * NHEAD + h;
#pragma unroll
                    for (int nt = 0; nt < 2; ++nt) {
                        int pix = pixW + nt * 16 + n16;
                        kbf[((size_t)bh * HWP + pix) * 32 + d] =
                            __float2bfloat16(acc[mt][nt][r] + bias);
                    }
                }
        } else {
#pragma unroll
            for (int mt = 0; mt < 4; ++mt)
#pragma unroll
                for (int r = 0; r < 4; ++r) {
                    int c2 = coBase - 768 + mt * 16 + quad * 4 + r;
                    float bias = qkv_b[c2 + 512];
                    int h = c2 >> 5, d = c2 & 31;
                    int bh = b * NHEAD + h;
                    __hip_bfloat16* vp = vtb + ((size_t)bh * 32 + d) * HWP + pixW;
#pragma unroll
                    for (int nt = 0; nt < 2; ++nt)
                        vp[nt * 16 + n16] = __float2bfloat16(acc[mt][nt][r] + bias);
                }
        }
    }
    grid_barrier(&bar[32]);

    // ================= Phase 2: attention (fused rel, deferred norm) ========
    {
        float* QrX = (float*)smem;                         // [4][16][68]
        float* QrY = (float*)(smem + 17408);               // [4][16][68]
        __hip_bfloat16* Pb = (__hip_bfloat16*)(smem + 34816);  // [4][16][40]

        const int bh = bid & 31;           // bh's 16 i-blocks share an XCD
        const int iblk = bid >> 5;
        const int i0 = (iblk * 4 + wv) * 16;
        const int xi0 = i0 & 31;
        const int yi0 = i0 >> 5;

        s8v aq = *reinterpret_cast<const s8v*>(
            qbf + ((size_t)bh * HWP + i0 + n16) * 32 + quad * 8);
        s8v aqT = *reinterpret_cast<const s8v*>(
            qbf + ((size_t)bh * HWP + (xi0 + n16) * 32 + yi0) * 32 + quad * 8);

#pragma unroll
        for (int t = 0; t < 4; ++t) {
            s8v bx = *reinterpret_cast<const s8v*>(krb + ((size_t)(t * 16 + n16)) * 32 + quad * 8);
            s8v by = *reinterpret_cast<const s8v*>(krb + ((size_t)(64 + t * 16 + n16)) * 32 + quad * 8);
            f32x4 cx = {0.f, 0.f, 0.f, 0.f}, cy = {0.f, 0.f, 0.f, 0.f};
            cx = __builtin_amdgcn_mfma_f32_16x16x32_bf16(aq, bx, cx, 0, 0, 0);
            cy = __builtin_amdgcn_mfma_f32_16x16x32_bf16(aqT, by, cy, 0, 0, 0);
#pragma unroll
            for (int r = 0; r < 4; ++r) {
                QrX[(wv * 16 + quad * 4 + r) * 68 + t * 16 + n16] = cx[r];
                QrY[(wv * 16 + quad * 4 + r) * 68 + t * 16 + n16] = cy[r];
            }
        }

        float rx0[4], rx1[4];
        int rybase[4];
#pragma unroll
        for (int r = 0; r < 4; ++r) {
            int xi = xi0 + quad * 4 + r;
            rx0[r] = QrX[(wv * 16 + quad * 4 + r) * 68 + n16 + 31 - xi];
            rx1[r] = QrX[(wv * 16 + quad * 4 + r) * 68 + n16 + 47 - xi];
            rybase[r] = 31 - xi;
        }

        float lsum[4] = {0.f, 0.f, 0.f, 0.f};
        f32x4 O0 = {0.f, 0.f, 0.f, 0.f}, O1 = {0.f, 0.f, 0.f, 0.f};

        const __hip_bfloat16* kbase = kbf + (size_t)bh * HWP * 32;
        const __hip_bfloat16* vbase = vtb + (size_t)bh * 32 * HWP;

        s8v bk0 = *reinterpret_cast<const s8v*>(kbase + ((size_t)n16 * 32 + quad * 8));
        s8v bk1 = *reinterpret_cast<const s8v*>(kbase + ((size_t)(16 + n16) * 32 + quad * 8));
        s8v bv0 = *reinterpret_cast<const s8v*>(vbase + ((size_t)n16 * HWP + quad * 8));
        s8v bv1 = *reinterpret_cast<const s8v*>(vbase + ((size_t)(n16 + 16) * HWP + quad * 8));

        for (int jt = 0; jt < 32; ++jt) {
            s8v cbk0 = bk0, cbk1 = bk1, cbv0 = bv0, cbv1 = bv1;
            if (jt < 31) {
                const int jn = (jt + 1) * 32;
                bk0 = *reinterpret_cast<const s8v*>(kbase + ((size_t)(jn + n16) * 32 + quad * 8));
                bk1 = *reinterpret_cast<const s8v*>(kbase + ((size_t)(jn + 16 + n16) * 32 + quad * 8));
                bv0 = *reinterpret_cast<const s8v*>(vbase + ((size_t)n16 * HWP + jn + quad * 8));
                bv1 = *reinterpret_cast<const s8v*>(vbase + ((size_t)(n16 + 16) * HWP + jn + quad * 8));
            }

            f32x4 s0 = {0.f, 0.f, 0.f, 0.f}, s1 = {0.f, 0.f, 0.f, 0.f};
            s0 = __builtin_amdgcn_mfma_f32_16x16x32_bf16(aq, cbk0, s0, 0, 0, 0);
            s1 = __builtin_amdgcn_mfma_f32_16x16x32_bf16(aq, cbk1, s1, 0, 0, 0);

#pragma unroll
            for (int r = 0; r < 4; ++r) {
                float ryv = QrY[(wv * 16 + quad * 4 + r) * 68 + jt + rybase[r]];
                float p0 = __expf(s0[r] + rx0[r] + ryv);
                float p1 = __expf(s1[r] + rx1[r] + ryv);
                lsum[r] += p0 + p1;
                Pb[(wv * 16 + quad * 4 + r) * 40 + n16]      = __float2bfloat16(p0);
                Pb[(wv * 16 + quad * 4 + r) * 40 + n16 + 16] = __float2bfloat16(p1);
            }
            s8v pA = *reinterpret_cast<const s8v*>(&Pb[(wv * 16 + n16) * 40 + quad * 8]);
            O0 = __builtin_amdgcn_mfma_f32_16x16x32_bf16(pA, cbv0, O0, 0, 0, 0);
            O1 = __builtin_amdgcn_mfma_f32_16x16x32_bf16(pA, cbv1, O1, 0, 0, 0);
        }

        const int b = bh >> 3, h = bh & 7;
#pragma unroll
        for (int r = 0; r < 4; ++r) {
            float l = lsum[r];
            l += __shfl_xor(l, 1);
            l += __shfl_xor(l, 2);
            l += __shfl_xor(l, 4);
            l += __shfl_xor(l, 8);
            float inv = 1.0f / l;
            int i = i0 + quad * 4 + r;
            int yi = i >> 5, xi = i & 31;
            __hip_bfloat16* op = attc + ((size_t)(b * 256 + h * 32 + yi) * 32 + xi) * 32;
            op[n16] = __float2bfloat16(O0[r] * inv);
            op[n16 + 16] = __float2bfloat16(O1[r] * inv);
        }
    }
    grid_barrier(&bar[64]);

    // ================= Phase 3: 1x1 conv (32o x 64pix) ======================
    {
        __hip_bfloat16* Ls = (__hip_bfloat16*)smem;   // [64][264]
        const int o0 = (bid & 7) * 32;
        const int pt = (bid >> 3) & 15;
        const int b = bid >> 7;
        const int p0 = pt * 64;
        const int oW = o0 + (wv >> 1) * 16;
        const int pL = (wv & 1) * 32;

#pragma unroll
        for (int pass = 0; pass < 8; ++pass) {
            int ch = pass * 32 + (tid >> 3);
            int pg = (tid & 7) * 8;
            s8v v = *reinterpret_cast<const s8v*>(
                attc + ((size_t)(b * 256 + ch) * HWP) + p0 + pg);
#pragma unroll
            for (int j = 0; j < 8; ++j)
                Ls[(pg + j) * 264 + ch] = ((const __hip_bfloat16*)&v)[j];
        }
        __syncthreads();

        f32x4 acc[2];
        acc[0] = (f32x4){0.f, 0.f, 0.f, 0.f};
        acc[1] = (f32x4){0.f, 0.f, 0.f, 0.f};

#pragma unroll
        for (int ks = 0; ks < 8; ++ks) {
            const int c0 = ks * 32 + quad * 8;
            s8v a0 = *reinterpret_cast<const s8v*>(Wab + (size_t)(oW + n16) * 256 + c0);
            s8v b0 = *reinterpret_cast<const s8v*>(&Ls[(pL + n16) * 264 + c0]);
            s8v b1 = *reinterpret_cast<const s8v*>(&Ls[(pL + 16 + n16) * 264 + c0]);
            acc[0] = __builtin_amdgcn_mfma_f32_16x16x32_bf16(a0, b0, acc[0], 0, 0, 0);
            acc[1] = __builtin_amdgcn_mfma_f32_16x16x32_bf16(a0, b1, acc[1], 0, 0, 0);
        }

#pragma unroll
        for (int r = 0; r < 4; ++r) {
            int o = oW + quad * 4 + r;
            float bias = att_b[o];
            float* op = out + ((size_t)(b * 512 + 256 + o)) * HWP;
#pragma unroll
            for (int nt = 0; nt < 2; ++nt)
                op[p0 + pL + nt * 16 + n16] = acc[nt][r] + bias;
        }
    }
}

extern "C" void kernel_launch(void* const* d_in, const int* in_sizes, int n_in,
                              void* d_out, int out_size, void* d_ws, size_t ws_size,
                              hipStream_t stream) {
    const float* x      = (const float*)d_in[0];
    const float* conv_w = (const float*)d_in[1];
    const float* conv_b = (const float*)d_in[2];
    const float* qkv_w  = (const float*)d_in[3];
    const float* qkv_b  = (const float*)d_in[4];
    const float* att_w  = (const float*)d_in[5];
    const float* att_b  = (const float*)d_in[6];
    const float* kr_x   = (const float*)d_in[7];
    const float* kr_y   = (const float*)d_in[8];
    float* out = (float*)d_out;

    char* base = (char*)d_ws;
    const size_t MB = 1u << 20;
    __hip_bfloat16* qbf  = (__hip_bfloat16*)(base + 0 * MB);
    __hip_bfloat16* kbf  = (__hip_bfloat16*)(base + 2 * MB);
    __hip_bfloat16* vtb  = (__hip_bfloat16*)(base + 4 * MB);
    __hip_bfloat16* xT   = (__hip_bfloat16*)(base + 6 * MB);
    __hip_bfloat16* Wb   = (__hip_bfloat16*)(base + 8 * MB);
    __hip_bfloat16* attc = (__hip_bfloat16*)(base + 11 * MB);
    __hip_bfloat16* Wab  = (__hip_bfloat16*)(base + 13 * MB);
    __hip_bfloat16* krb  = (__hip_bfloat16*)(base + 14 * MB);
    unsigned* bar        = (unsigned*)(base + 15 * MB);   // 3 counters, 128B apart

    hipMemsetAsync(bar, 0, 384, stream);
    mega_kernel<<<dim3(NBLK), 256, 0, stream>>>(
        x, conv_w, conv_b, qkv_w, qkv_b, att_w, att_b, kr_x, kr_y, out,
        qbf, kbf, vtb, xT, Wb, Wab, krb, attc, bar);
}

// Round 11
// 139.478 us; speedup vs baseline: 2.1490x; 2.1490x over previous
//
#include <hip/hip_runtime.h>
#include <hip/hip_bf16.h>
#include <math.h>

#define BN 4
#define CIN 128
#define HH 32
#define WW 32
#define HWP 1024
#define NHEAD 8

typedef __attribute__((ext_vector_type(8))) short s8v;
typedef __attribute__((ext_vector_type(4))) float f32x4;

// ---------------- P: all prep in one kernel ----------------
// blocks [0,4608): Wb;  [4608,4744): xT;  [4744,5000): Wab;  5000: krb
__global__ __launch_bounds__(256) void prep_all(
    const float* __restrict__ x,
    const float* __restrict__ conv_w, const float* __restrict__ qkv_w,
    const float* __restrict__ att_w,
    const float* __restrict__ kr_x, const float* __restrict__ kr_y,
    __hip_bfloat16* __restrict__ xT, __hip_bfloat16* __restrict__ Wb,
    __hip_bfloat16* __restrict__ Wab, __hip_bfloat16* __restrict__ krb)
{
    const int bid = blockIdx.x;
    const int tid = threadIdx.x;

    if (bid < 4608) {
        int g = bid * 256 + tid;               // 1024*1152
        int co = g / 1152;
        int k = g - co * 1152;
        int kk = k >> 7, ci = k & 127;         // kk = ky*3+kx
        float v;
        if (co < 256) v = conv_w[((size_t)(co * 128 + ci) * 9) + kk];
        else          v = qkv_w[((size_t)((co - 256) * 128 + ci) * 9) + kk];
        Wb[(size_t)co * 1152 + k] = __float2bfloat16(v);
    } else if (bid < 4744) {
        __shared__ float xs[CIN][33];
        int rel = bid - 4608;
        int yy = rel >> 2;
        int b = rel & 3;
        const bool inner = (yy >= 1 && yy <= 32);
        if (inner) {
            for (int idx = tid; idx < CIN * 32; idx += 256) {
                int ci = idx >> 5, xx = idx & 31;
                xs[ci][xx] = x[((size_t)(b * CIN + ci) * HH + (yy - 1)) * WW + xx];
            }
        }
        __syncthreads();
        for (int idx = tid; idx < 34 * 128; idx += 256) {
            int xx = idx >> 7, ci = idx & 127;
            float v = 0.f;
            if (inner && xx >= 1 && xx <= 32) v = xs[ci][xx - 1];
            xT[((size_t)(b * 34 + yy) * 34 + xx) * 128 + ci] = __float2bfloat16(v);
        }
    } else if (bid < 5000) {
        int g = (bid - 4744) * 256 + tid;      // 65536
        Wab[g] = __float2bfloat16(att_w[g]);
    } else {
        // krb[axis][64][32]; col 63 zeroed (d_ws is poisoned!)
        for (int idx = tid; idx < 2 * 64 * 32; idx += 256) {
            int axis = idx >> 11;
            int col = (idx >> 5) & 63;
            int d = idx & 31;
            float v = 0.f;
            if (col < 63) v = axis ? kr_y[col * 32 + d] : kr_x[col * 32 + d];
            krb[idx] = __float2bfloat16(v);
        }
    }
}

// ---------------- K1: MFMA implicit-GEMM 3x3 conv ----------------
__global__ __launch_bounds__(256) void conv_gemm(
    const __hip_bfloat16* __restrict__ Wb, const __hip_bfloat16* __restrict__ xT,
    const float* __restrict__ conv_b, const float* __restrict__ qkv_b,
    float* __restrict__ out,
    __hip_bfloat16* __restrict__ qbf, __hip_bfloat16* __restrict__ kbf,
    __hip_bfloat16* __restrict__ vtb)
{
    __shared__ __align__(16) __hip_bfloat16 As[128 * 128];
    __shared__ __align__(16) __hip_bfloat16 Bs[128 * 128];

    const int tid = threadIdx.x;
    const int wv = tid >> 6;
    const int lane = tid & 63;
    const int n16 = lane & 15;
    const int quad = lane >> 4;
    const int co0 = blockIdx.x * 128;
    const int y0 = blockIdx.y * 4;
    const int b = blockIdx.z;
    const int mh = wv >> 1, nh = wv & 1;

    const int rbase = tid >> 4;
    const int hh = tid & 15;
    const int swz = (hh ^ rbase) * 8;
    const __hip_bfloat16* aGbase = Wb + (size_t)(co0 + rbase) * 1152 + hh * 8;

    f32x4 acc[4][4];
#pragma unroll
    for (int i = 0; i < 4; ++i)
#pragma unroll
        for (int j = 0; j < 4; ++j) acc[i][j] = (f32x4){0.f, 0.f, 0.f, 0.f};

    s8v ra[8], rb[8];

    auto load_tile = [&](int kk, s8v* la, s8v* lb) {
        const int ky = kk / 3, kx = kk - ky * 3;
#pragma unroll
        for (int i = 0; i < 8; ++i)
            la[i] = *reinterpret_cast<const s8v*>(aGbase + (size_t)(16 * i) * 1152 + kk * 128);
#pragma unroll
        for (int i = 0; i < 8; ++i) {
            int p = rbase + 16 * i;
            int row = y0 + (p >> 5) + ky;
            int xx = (p & 31) + kx;
            lb[i] = *reinterpret_cast<const s8v*>(
                xT + ((size_t)(b * 34 + row) * 34 + xx) * 128 + hh * 8);
        }
    };

    load_tile(0, ra, rb);

    for (int s = 0; s < 9; ++s) {
        __syncthreads();
#pragma unroll
        for (int i = 0; i < 8; ++i) {
            *reinterpret_cast<s8v*>(&As[(rbase + 16 * i) * 128 + swz]) = ra[i];
            *reinterpret_cast<s8v*>(&Bs[(rbase + 16 * i) * 128 + swz]) = rb[i];
        }
        __syncthreads();
        if (s < 8) load_tile(s + 1, ra, rb);

#pragma unroll
        for (int ksub = 0; ksub < 4; ++ksub) {
            const int chunk = ((ksub * 4 + quad) ^ n16) * 8;
            s8v af[4], bfr[4];
#pragma unroll
            for (int mt = 0; mt < 4; ++mt)
                af[mt] = *reinterpret_cast<const s8v*>(&As[(mh * 64 + mt * 16 + n16) * 128 + chunk]);
#pragma unroll
            for (int nt = 0; nt < 4; ++nt)
                bfr[nt] = *reinterpret_cast<const s8v*>(&Bs[(nh * 64 + nt * 16 + n16) * 128 + chunk]);
#pragma unroll
            for (int mt = 0; mt < 4; ++mt)
#pragma unroll
                for (int nt = 0; nt < 4; ++nt)
                    acc[mt][nt] = __builtin_amdgcn_mfma_f32_16x16x32_bf16(af[mt], bfr[nt], acc[mt][nt], 0, 0, 0);
        }
    }

    const int coBase = co0 + mh * 64;
    const int pixBase = y0 * 32 + nh * 64;
    const int seg = coBase >> 8;

    if (seg == 0) {
#pragma unroll
        for (int mt = 0; mt < 4; ++mt)
#pragma unroll
            for (int r = 0; r < 4; ++r) {
                int co = coBase + mt * 16 + quad * 4 + r;
                float bias = conv_b[co];
                float* op = out + (size_t)(b * 512 + co) * HWP + pixBase;
#pragma unroll
                for (int nt = 0; nt < 4; ++nt)
                    op[nt * 16 + n16] = acc[mt][nt][r] + bias;
            }
    } else if (seg == 1) {
        const float scale = 0.17677669529663687f;
#pragma unroll
        for (int mt = 0; mt < 4; ++mt)
#pragma unroll
            for (int r = 0; r < 4; ++r) {
                int c2 = coBase - 256 + mt * 16 + quad * 4 + r;
                float bias = qkv_b[c2];
                int h = c2 >> 5, d = c2 & 31;
                int bh = b * NHEAD + h;
#pragma unroll
                for (int nt = 0; nt < 4; ++nt) {
                    int pix = pixBase + nt * 16 + n16;
                    qbf[((size_t)bh * HWP + pix) * 32 + d] =
                        __float2bfloat16((acc[mt][nt][r] + bias) * scale);
                }
            }
    } else if (seg == 2) {
#pragma unroll
        for (int mt = 0; mt < 4; ++mt)
#pragma unroll
            for (int r = 0; r < 4; ++r) {
                int c2 = coBase - 512 + mt * 16 + quad * 4 + r;
                float bias = qkv_b[c2 + 256];
                int h = c2 >> 5, d = c2 & 31;
                int bh = b * NHEAD + h;
#pragma unroll
                for (int nt = 0; nt < 4; ++nt) {
                    int pix = pixBase + nt * 16 + n16;
                    kbf[((size_t)bh * HWP + pix) * 32 + d] =
                        __float2bfloat16(acc[mt][nt][r] + bias);
                }
            }
    } else {
#pragma unroll
        for (int mt = 0; mt < 4; ++mt)
#pragma unroll
            for (int r = 0; r < 4; ++r) {
                int c2 = coBase - 768 + mt * 16 + quad * 4 + r;
                float bias = qkv_b[c2 + 512];
                int h = c2 >> 5, d = c2 & 31;
                int bh = b * NHEAD + h;
                __hip_bfloat16* vp = vtb + ((size_t)bh * 32 + d) * HWP + pixBase;
#pragma unroll
                for (int nt = 0; nt < 4; ++nt)
                    vp[nt * 16 + n16] = __float2bfloat16(acc[mt][nt][r] + bias);
            }
    }
}

// ---------------- K2: MFMA flash attention with fused rel logits ----------
__global__ __launch_bounds__(256) void attn_kernel(
    const __hip_bfloat16* __restrict__ qbf, const __hip_bfloat16* __restrict__ kbf,
    const __hip_bfloat16* __restrict__ vtb, const __hip_bfloat16* __restrict__ krb,
    __hip_bfloat16* __restrict__ attc)
{
    __shared__ __align__(16) float QrX[4][16][68];
    __shared__ __align__(16) float QrY[4][16][68];
    __shared__ __align__(16) __hip_bfloat16 Pb[4][16][40];

    const int tid = threadIdx.x;
    const int wv = tid >> 6;
    const int lane = tid & 63;
    const int n16 = lane & 15;
    const int quad = lane >> 4;
    const int bh = blockIdx.x;
    const int i0 = (blockIdx.y * 4 + wv) * 16;
    const int xi0 = i0 & 31;
    const int yi0 = i0 >> 5;

    s8v aq = *reinterpret_cast<const s8v*>(
        qbf + ((size_t)bh * HWP + i0 + n16) * 32 + quad * 8);
    s8v aqT = *reinterpret_cast<const s8v*>(
        qbf + ((size_t)bh * HWP + (xi0 + n16) * 32 + yi0) * 32 + quad * 8);

#pragma unroll
    for (int t = 0; t < 4; ++t) {
        s8v bx = *reinterpret_cast<const s8v*>(krb + ((size_t)(t * 16 + n16)) * 32 + quad * 8);
        s8v by = *reinterpret_cast<const s8v*>(krb + ((size_t)(64 + t * 16 + n16)) * 32 + quad * 8);
        f32x4 cx = {0.f, 0.f, 0.f, 0.f}, cy = {0.f, 0.f, 0.f, 0.f};
        cx = __builtin_amdgcn_mfma_f32_16x16x32_bf16(aq, bx, cx, 0, 0, 0);
        cy = __builtin_amdgcn_mfma_f32_16x16x32_bf16(aqT, by, cy, 0, 0, 0);
#pragma unroll
        for (int r = 0; r < 4; ++r) {
            QrX[wv][quad * 4 + r][t * 16 + n16] = cx[r];
            QrY[wv][quad * 4 + r][t * 16 + n16] = cy[r];
        }
    }

    float rx0[4], rx1[4];
    int rybase[4];
#pragma unroll
    for (int r = 0; r < 4; ++r) {
        int xi = xi0 + quad * 4 + r;
        rx0[r] = QrX[wv][quad * 4 + r][n16 + 31 - xi];
        rx1[r] = QrX[wv][quad * 4 + r][n16 + 47 - xi];
        rybase[r] = 31 - xi;
    }

    float lsum[4] = {0.f, 0.f, 0.f, 0.f};
    f32x4 O0 = {0.f, 0.f, 0.f, 0.f}, O1 = {0.f, 0.f, 0.f, 0.f};

    const __hip_bfloat16* kbase = kbf + (size_t)bh * HWP * 32;
    const __hip_bfloat16* vbase = vtb + (size_t)bh * 32 * HWP;

    s8v bk0 = *reinterpret_cast<const s8v*>(kbase + ((size_t)n16 * 32 + quad * 8));
    s8v bk1 = *reinterpret_cast<const s8v*>(kbase + ((size_t)(16 + n16) * 32 + quad * 8));
    s8v bv0 = *reinterpret_cast<const s8v*>(vbase + ((size_t)n16 * HWP + quad * 8));
    s8v bv1 = *reinterpret_cast<const s8v*>(vbase + ((size_t)(n16 + 16) * HWP + quad * 8));

    for (int jt = 0; jt < 32; ++jt) {
        s8v cbk0 = bk0, cbk1 = bk1, cbv0 = bv0, cbv1 = bv1;
        if (jt < 31) {
            const int jn = (jt + 1) * 32;
            bk0 = *reinterpret_cast<const s8v*>(kbase + ((size_t)(jn + n16) * 32 + quad * 8));
            bk1 = *reinterpret_cast<const s8v*>(kbase + ((size_t)(jn + 16 + n16) * 32 + quad * 8));
            bv0 = *reinterpret_cast<const s8v*>(vbase + ((size_t)n16 * HWP + jn + quad * 8));
            bv1 = *reinterpret_cast<const s8v*>(vbase + ((size_t)(n16 + 16) * HWP + jn + quad * 8));
        }

        f32x4 s0 = {0.f, 0.f, 0.f, 0.f}, s1 = {0.f, 0.f, 0.f, 0.f};
        s0 = __builtin_amdgcn_mfma_f32_16x16x32_bf16(aq, cbk0, s0, 0, 0, 0);
        s1 = __builtin_amdgcn_mfma_f32_16x16x32_bf16(aq, cbk1, s1, 0, 0, 0);

#pragma unroll
        for (int r = 0; r < 4; ++r) {
            float ryv = QrY[wv][quad * 4 + r][jt + rybase[r]];
            float p0 = __expf(s0[r] + rx0[r] + ryv);
            float p1 = __expf(s1[r] + rx1[r] + ryv);
            lsum[r] += p0 + p1;
            Pb[wv][quad * 4 + r][n16]      = __float2bfloat16(p0);
            Pb[wv][quad * 4 + r][n16 + 16] = __float2bfloat16(p1);
        }
        s8v pA = *reinterpret_cast<const s8v*>(&Pb[wv][n16][quad * 8]);
        O0 = __builtin_amdgcn_mfma_f32_16x16x32_bf16(pA, cbv0, O0, 0, 0, 0);
        O1 = __builtin_amdgcn_mfma_f32_16x16x32_bf16(pA, cbv1, O1, 0, 0, 0);
    }

    const int b = bh >> 3, h = bh & 7;
#pragma unroll
    for (int r = 0; r < 4; ++r) {
        float l = lsum[r];
        l += __shfl_xor(l, 1);
        l += __shfl_xor(l, 2);
        l += __shfl_xor(l, 4);
        l += __shfl_xor(l, 8);
        float inv = 1.0f / l;
        int i = i0 + quad * 4 + r;
        int yi = i >> 5, xi = i & 31;
        __hip_bfloat16* op = attc + ((size_t)(b * 256 + h * 32 + yi) * 32 + xi) * 32;
        op[n16] = __float2bfloat16(O0[r] * inv);
        op[n16 + 16] = __float2bfloat16(O1[r] * inv);
    }
}

// ---------------- K3: 1x1 conv MFMA GEMM with fused transpose staging -------
__global__ __launch_bounds__(256) void conv1x1_gemm(
    const __hip_bfloat16* __restrict__ Wab, const __hip_bfloat16* __restrict__ attc,
    const float* __restrict__ att_b, float* __restrict__ out)
{
    __shared__ __align__(16) __hip_bfloat16 Ls[64][264];

    const int tid = threadIdx.x;
    const int wv = tid >> 6;
    const int lane = tid & 63;
    const int n16 = lane & 15;
    const int quad = lane >> 4;
    const int o0 = blockIdx.x * 64;
    const int p0 = blockIdx.y * 64;
    const int b = blockIdx.z;
    const int oW = o0 + (wv >> 1) * 32;
    const int pL = (wv & 1) * 32;

#pragma unroll
    for (int pass = 0; pass < 8; ++pass) {
        int ch = pass * 32 + (tid >> 3);
        int pg = (tid & 7) * 8;
        s8v v = *reinterpret_cast<const s8v*>(
            attc + ((size_t)(b * 256 + ch) * HWP) + p0 + pg);
#pragma unroll
        for (int j = 0; j < 8; ++j)
            Ls[pg + j][ch] = ((const __hip_bfloat16*)&v)[j];
    }
    __syncthreads();

    f32x4 acc[2][2];
#pragma unroll
    for (int i = 0; i < 2; ++i)
#pragma unroll
        for (int j = 0; j < 2; ++j) acc[i][j] = (f32x4){0.f, 0.f, 0.f, 0.f};

#pragma unroll
    for (int ks = 0; ks < 8; ++ks) {
        const int c0 = ks * 32 + quad * 8;
        s8v a0 = *reinterpret_cast<const s8v*>(Wab + (size_t)(oW + n16) * 256 + c0);
        s8v a1 = *reinterpret_cast<const s8v*>(Wab + (size_t)(oW + 16 + n16) * 256 + c0);
        s8v b0 = *reinterpret_cast<const s8v*>(&Ls[pL + n16][c0]);
        s8v b1 = *reinterpret_cast<const s8v*>(&Ls[pL + 16 + n16][c0]);
        acc[0][0] = __builtin_amdgcn_mfma_f32_16x16x32_bf16(a0, b0, acc[0][0], 0, 0, 0);
        acc[0][1] = __builtin_amdgcn_mfma_f32_16x16x32_bf16(a0, b1, acc[0][1], 0, 0, 0);
        acc[1][0] = __builtin_amdgcn_mfma_f32_16x16x32_bf16(a1, b0, acc[1][0], 0, 0, 0);
        acc[1][1] = __builtin_amdgcn_mfma_f32_16x16x32_bf16(a1, b1, acc[1][1], 0, 0, 0);
    }

#pragma unroll
    for (int mt = 0; mt < 2; ++mt)
#pragma unroll
        for (int r = 0; r < 4; ++r) {
            int o = oW + mt * 16 + quad * 4 + r;
            float bias = att_b[o];
            float* op = out + ((size_t)(b * 512 + 256 + o)) * HWP;
#pragma unroll
            for (int nt = 0; nt < 2; ++nt)
                op[p0 + pL + nt * 16 + n16] = acc[mt][nt][r] + bias;
        }
}

extern "C" void kernel_launch(void* const* d_in, const int* in_sizes, int n_in,
                              void* d_out, int out_size, void* d_ws, size_t ws_size,
                              hipStream_t stream) {
    const float* x      = (const float*)d_in[0];
    const float* conv_w = (const float*)d_in[1];
    const float* conv_b = (const float*)d_in[2];
    const float* qkv_w  = (const float*)d_in[3];
    const float* qkv_b  = (const float*)d_in[4];
    const float* att_w  = (const float*)d_in[5];
    const float* att_b  = (const float*)d_in[6];
    const float* kr_x   = (const float*)d_in[7];
    const float* kr_y   = (const float*)d_in[8];
    float* out = (float*)d_out;

    char* base = (char*)d_ws;
    const size_t MB = 1u << 20;
    __hip_bfloat16* qbf  = (__hip_bfloat16*)(base + 0 * MB);
    __hip_bfloat16* kbf  = (__hip_bfloat16*)(base + 2 * MB);
    __hip_bfloat16* vtb  = (__hip_bfloat16*)(base + 4 * MB);
    __hip_bfloat16* xT   = (__hip_bfloat16*)(base + 6 * MB);
    __hip_bfloat16* Wb   = (__hip_bfloat16*)(base + 8 * MB);
    __hip_bfloat16* attc = (__hip_bfloat16*)(base + 11 * MB);
    __hip_bfloat16* Wab  = (__hip_bfloat16*)(base + 13 * MB);
    __hip_bfloat16* krb  = (__hip_bfloat16*)(base + 14 * MB);

    prep_all<<<dim3(5001), 256, 0, stream>>>(
        x, conv_w, qkv_w, att_w, kr_x, kr_y, xT, Wb, Wab, krb);
    conv_gemm<<<dim3(8, 8, 4), 256, 0, stream>>>(
        Wb, xT, conv_b, qkv_b, out, qbf, kbf, vtb);
    attn_kernel<<<dim3(32, 16), 256, 0, stream>>>(qbf, kbf, vtb, krb, attc);
    conv1x1_gemm<<<dim3(4, 16, 4), 256, 0, stream>>>(Wab, attc, att_b, out);
}

// Round 12
// 134.010 us; speedup vs baseline: 2.2367x; 1.0408x over previous
//
#include <hip/hip_runtime.h>
#include <hip/hip_bf16.h>
#include <math.h>

#define BN 4
#define CIN 128
#define HH 32
#define WW 32
#define HWP 1024
#define NHEAD 8

typedef __attribute__((ext_vector_type(8))) short s8v;
typedef __attribute__((ext_vector_type(4))) float f32x4;

// ---------------- P: all prep in one kernel ----------------
// blocks [0,128): Wb (8 co each, coalesced read + LDS transpose)
// [128,264): xT;  [264,328): Wab (float4);  328: krb
__global__ __launch_bounds__(256) void prep_all(
    const float* __restrict__ x,
    const float* __restrict__ conv_w, const float* __restrict__ qkv_w,
    const float* __restrict__ att_w,
    const float* __restrict__ kr_x, const float* __restrict__ kr_y,
    __hip_bfloat16* __restrict__ xT, __hip_bfloat16* __restrict__ Wb,
    __hip_bfloat16* __restrict__ Wab, __hip_bfloat16* __restrict__ krb)
{
    const int bid = blockIdx.x;
    const int tid = threadIdx.x;

    if (bid < 128) {
        // 8 co-rows: read 8*1152 floats coalesced (source order ci*9+kk),
        // LDS-transpose to (kk*128+ci), write out coalesced.
        __shared__ __hip_bfloat16 Ws[8 * 1152];   // 18 KB
        const int co0 = bid * 8;
        const float* src = (co0 < 256) ? (conv_w + (size_t)co0 * 1152)
                                       : (qkv_w + (size_t)(co0 - 256) * 1152);
#pragma unroll
        for (int pass = 0; pass < 36; ++pass) {
            int idx = pass * 256 + tid;            // 0..9215
            float v = src[idx];
            int col = idx / 1152;                  // co_local
            int r = idx - col * 1152;
            int ci = r / 9;
            int kk = r - ci * 9;
            Ws[col * 1152 + kk * 128 + ci] = __float2bfloat16(v);
        }
        __syncthreads();
        const unsigned* Lu = (const unsigned*)Ws;
        unsigned* Ou = (unsigned*)(Wb + (size_t)co0 * 1152);
#pragma unroll
        for (int pass = 0; pass < 18; ++pass)
            Ou[pass * 256 + tid] = Lu[pass * 256 + tid];
    } else if (bid < 264) {
        __shared__ float xs[CIN][33];
        int rel = bid - 128;
        int yy = rel >> 2;
        int b = rel & 3;
        const bool inner = (yy >= 1 && yy <= 32);
        if (inner) {
            for (int idx = tid; idx < CIN * 32; idx += 256) {
                int ci = idx >> 5, xx = idx & 31;
                xs[ci][xx] = x[((size_t)(b * CIN + ci) * HH + (yy - 1)) * WW + xx];
            }
        }
        __syncthreads();
        for (int idx = tid; idx < 34 * 128; idx += 256) {
            int xx = idx >> 7, ci = idx & 127;
            float v = 0.f;
            if (inner && xx >= 1 && xx <= 32) v = xs[ci][xx - 1];
            xT[((size_t)(b * 34 + yy) * 34 + xx) * 128 + ci] = __float2bfloat16(v);
        }
    } else if (bid < 328) {
        int g = ((bid - 264) * 256 + tid) * 4;     // 65536 total
        float4 v = *(const float4*)(att_w + g);
        Wab[g + 0] = __float2bfloat16(v.x);
        Wab[g + 1] = __float2bfloat16(v.y);
        Wab[g + 2] = __float2bfloat16(v.z);
        Wab[g + 3] = __float2bfloat16(v.w);
    } else {
        // krb[axis][64][32]; col 63 zeroed (d_ws is poisoned!)
        for (int idx = tid; idx < 2 * 64 * 32; idx += 256) {
            int axis = idx >> 11;
            int col = (idx >> 5) & 63;
            int d = idx & 31;
            float v = 0.f;
            if (col < 63) v = axis ? kr_y[col * 32 + d] : kr_x[col * 32 + d];
            krb[idx] = __float2bfloat16(v);
        }
    }
}

// ---------------- K1: MFMA implicit-GEMM 3x3 conv (128co x 64pix) ----------
// grid 512 1-D; 48 KB LDS -> 2 blocks/CU co-resident (validated in R10 mega).
__global__ __launch_bounds__(256) void conv_gemm(
    const __hip_bfloat16* __restrict__ Wb, const __hip_bfloat16* __restrict__ xT,
    const float* __restrict__ conv_b, const float* __restrict__ qkv_b,
    float* __restrict__ out,
    __hip_bfloat16* __restrict__ qbf, __hip_bfloat16* __restrict__ kbf,
    __hip_bfloat16* __restrict__ vtb)
{
    __shared__ __align__(16) __hip_bfloat16 As[128 * 128];   // 32 KB
    __shared__ __align__(16) __hip_bfloat16 Bs[64 * 128];    // 16 KB

    const int tid = threadIdx.x;
    const int wv = tid >> 6;
    const int lane = tid & 63;
    const int n16 = lane & 15;
    const int quad = lane >> 4;
    const int bid = blockIdx.x;
    const int ph = bid & 1;
    const int b = (bid >> 1) & 3;
    const int yt = (bid >> 3) & 7;
    const int ct = bid >> 6;
    const int co0 = ct * 128;
    const int pixBase = yt * 128 + ph * 64;
    const int row0 = pixBase >> 5;
    const int mh = wv >> 1, nh = wv & 1;
    const int rbase = tid >> 4;
    const int hh = tid & 15;
    const int swz = (hh ^ rbase) * 8;
    const __hip_bfloat16* aGbase = Wb + (size_t)(co0 + rbase) * 1152 + hh * 8;

    f32x4 acc[4][2];
#pragma unroll
    for (int i = 0; i < 4; ++i)
#pragma unroll
        for (int j = 0; j < 2; ++j) acc[i][j] = (f32x4){0.f, 0.f, 0.f, 0.f};

    s8v ra[8], rb2[4];
    auto load_tile = [&](int kk, s8v* la, s8v* lb) {
        const int ky = kk / 3, kx = kk - ky * 3;
#pragma unroll
        for (int i = 0; i < 8; ++i)
            la[i] = *reinterpret_cast<const s8v*>(aGbase + (size_t)(16 * i) * 1152 + kk * 128);
#pragma unroll
        for (int i = 0; i < 4; ++i) {
            int p = rbase + 16 * i;
            lb[i] = *reinterpret_cast<const s8v*>(
                xT + ((size_t)(b * 34 + row0 + (p >> 5) + ky) * 34 + (p & 31) + kx) * 128 + hh * 8);
        }
    };

    load_tile(0, ra, rb2);

    for (int s = 0; s < 9; ++s) {
        __syncthreads();
#pragma unroll
        for (int i = 0; i < 8; ++i)
            *reinterpret_cast<s8v*>(&As[(rbase + 16 * i) * 128 + swz]) = ra[i];
#pragma unroll
        for (int i = 0; i < 4; ++i)
            *reinterpret_cast<s8v*>(&Bs[(rbase + 16 * i) * 128 + swz]) = rb2[i];
        __syncthreads();
        if (s < 8) load_tile(s + 1, ra, rb2);

#pragma unroll
        for (int ksub = 0; ksub < 4; ++ksub) {
            const int chunk = ((ksub * 4 + quad) ^ n16) * 8;
            s8v af[4], bfr[2];
#pragma unroll
            for (int mt = 0; mt < 4; ++mt)
                af[mt] = *reinterpret_cast<const s8v*>(&As[(mh * 64 + mt * 16 + n16) * 128 + chunk]);
#pragma unroll
            for (int nt = 0; nt < 2; ++nt)
                bfr[nt] = *reinterpret_cast<const s8v*>(&Bs[(nh * 32 + nt * 16 + n16) * 128 + chunk]);
#pragma unroll
            for (int mt = 0; mt < 4; ++mt)
#pragma unroll
                for (int nt = 0; nt < 2; ++nt)
                    acc[mt][nt] = __builtin_amdgcn_mfma_f32_16x16x32_bf16(af[mt], bfr[nt], acc[mt][nt], 0, 0, 0);
        }
    }

    const int coBase = co0 + mh * 64;
    const int pixW = pixBase + nh * 32;
    const int seg = coBase >> 8;

    if (seg == 0) {
#pragma unroll
        for (int mt = 0; mt < 4; ++mt)
#pragma unroll
            for (int r = 0; r < 4; ++r) {
                int co = coBase + mt * 16 + quad * 4 + r;
                float bias = conv_b[co];
                float* op = out + (size_t)(b * 512 + co) * HWP + pixW;
#pragma unroll
                for (int nt = 0; nt < 2; ++nt)
                    op[nt * 16 + n16] = acc[mt][nt][r] + bias;
            }
    } else if (seg == 1) {
        const float scale = 0.17677669529663687f;
#pragma unroll
        for (int mt = 0; mt < 4; ++mt)
#pragma unroll
            for (int r = 0; r < 4; ++r) {
                int c2 = coBase - 256 + mt * 16 + quad * 4 + r;
                float bias = qkv_b[c2];
                int h = c2 >> 5, d = c2 & 31;
                int bh = b * NHEAD + h;
#pragma unroll
                for (int nt = 0; nt < 2; ++nt) {
                    int pix = pixW + nt * 16 + n16;
                    qbf[((size_t)bh * HWP + pix) * 32 + d] =
                        __float2bfloat16((acc[mt][nt][r] + bias) * scale);
                }
            }
    } else if (seg == 2) {
#pragma unroll
        for (int mt = 0; mt < 4; ++mt)
#pragma unroll
            for (int r = 0; r < 4; ++r) {
                int c2 = coBase - 512 + mt * 16 + quad * 4 + r;
                float bias = qkv_b[c2 + 256];
                int h = c2 >> 5, d = c2 & 31;
                int bh = b * NHEAD + h;
#pragma unroll
                for (int nt = 0; nt < 2; ++nt) {
                    int pix = pixW + nt * 16 + n16;
                    kbf[((size_t)bh * HWP + pix) * 32 + d] =
                        __float2bfloat16(acc[mt][nt][r] + bias);
                }
            }
    } else {
#pragma unroll
        for (int mt = 0; mt < 4; ++mt)
#pragma unroll
            for (int r = 0; r < 4; ++r) {
                int c2 = coBase - 768 + mt * 16 + quad * 4 + r;
                float bias = qkv_b[c2 + 512];
                int h = c2 >> 5, d = c2 & 31;
                int bh = b * NHEAD + h;
                __hip_bfloat16* vp = vtb + ((size_t)bh * 32 + d) * HWP + pixW;
#pragma unroll
                for (int nt = 0; nt < 2; ++nt)
                    vp[nt * 16 + n16] = __float2bfloat16(acc[mt][nt][r] + bias);
            }
    }
}

// ---------------- K2: MFMA flash attention with fused rel logits ----------
__global__ __launch_bounds__(256) void attn_kernel(
    const __hip_bfloat16* __restrict__ qbf, const __hip_bfloat16* __restrict__ kbf,
    const __hip_bfloat16* __restrict__ vtb, const __hip_bfloat16* __restrict__ krb,
    __hip_bfloat16* __restrict__ attc)
{
    __shared__ __align__(16) float QrX[4][16][68];
    __shared__ __align__(16) float QrY[4][16][68];
    __shared__ __align__(16) __hip_bfloat16 Pb[4][16][40];

    const int tid = threadIdx.x;
    const int wv = tid >> 6;
    const int lane = tid & 63;
    const int n16 = lane & 15;
    const int quad = lane >> 4;
    const int bh = blockIdx.x;
    const int i0 = (blockIdx.y * 4 + wv) * 16;
    const int xi0 = i0 & 31;
    const int yi0 = i0 >> 5;

    s8v aq = *reinterpret_cast<const s8v*>(
        qbf + ((size_t)bh * HWP + i0 + n16) * 32 + quad * 8);
    s8v aqT = *reinterpret_cast<const s8v*>(
        qbf + ((size_t)bh * HWP + (xi0 + n16) * 32 + yi0) * 32 + quad * 8);

#pragma unroll
    for (int t = 0; t < 4; ++t) {
        s8v bx = *reinterpret_cast<const s8v*>(krb + ((size_t)(t * 16 + n16)) * 32 + quad * 8);
        s8v by = *reinterpret_cast<const s8v*>(krb + ((size_t)(64 + t * 16 + n16)) * 32 + quad * 8);
        f32x4 cx = {0.f, 0.f, 0.f, 0.f}, cy = {0.f, 0.f, 0.f, 0.f};
        cx = __builtin_amdgcn_mfma_f32_16x16x32_bf16(aq, bx, cx, 0, 0, 0);
        cy = __builtin_amdgcn_mfma_f32_16x16x32_bf16(aqT, by, cy, 0, 0, 0);
#pragma unroll
        for (int r = 0; r < 4; ++r) {
            QrX[wv][quad * 4 + r][t * 16 + n16] = cx[r];
            QrY[wv][quad * 4 + r][t * 16 + n16] = cy[r];
        }
    }

    float rx0[4], rx1[4];
    int rybase[4];
#pragma unroll
    for (int r = 0; r < 4; ++r) {
        int xi = xi0 + quad * 4 + r;
        rx0[r] = QrX[wv][quad * 4 + r][n16 + 31 - xi];
        rx1[r] = QrX[wv][quad * 4 + r][n16 + 47 - xi];
        rybase[r] = 31 - xi;
    }

    float lsum[4] = {0.f, 0.f, 0.f, 0.f};
    f32x4 O0 = {0.f, 0.f, 0.f, 0.f}, O1 = {0.f, 0.f, 0.f, 0.f};

    const __hip_bfloat16* kbase = kbf + (size_t)bh * HWP * 32;
    const __hip_bfloat16* vbase = vtb + (size_t)bh * 32 * HWP;

    s8v bk0 = *reinterpret_cast<const s8v*>(kbase + ((size_t)n16 * 32 + quad * 8));
    s8v bk1 = *reinterpret_cast<const s8v*>(kbase + ((size_t)(16 + n16) * 32 + quad * 8));
    s8v bv0 = *reinterpret_cast<const s8v*>(vbase + ((size_t)n16 * HWP + quad * 8));
    s8v bv1 = *reinterpret_cast<const s8v*>(vbase + ((size_t)(n16 + 16) * HWP + quad * 8));

    for (int jt = 0; jt < 32; ++jt) {
        s8v cbk0 = bk0, cbk1 = bk1, cbv0 = bv0, cbv1 = bv1;
        if (jt < 31) {
            const int jn = (jt + 1) * 32;
            bk0 = *reinterpret_cast<const s8v*>(kbase + ((size_t)(jn + n16) * 32 + quad * 8));
            bk1 = *reinterpret_cast<const s8v*>(kbase + ((size_t)(jn + 16 + n16) * 32 + quad * 8));
            bv0 = *reinterpret_cast<const s8v*>(vbase + ((size_t)n16 * HWP + jn + quad * 8));
            bv1 = *reinterpret_cast<const s8v*>(vbase + ((size_t)(n16 + 16) * HWP + jn + quad * 8));
        }

        f32x4 s0 = {0.f, 0.f, 0.f, 0.f}, s1 = {0.f, 0.f, 0.f, 0.f};
        s0 = __builtin_amdgcn_mfma_f32_16x16x32_bf16(aq, cbk0, s0, 0, 0, 0);
        s1 = __builtin_amdgcn_mfma_f32_16x16x32_bf16(aq, cbk1, s1, 0, 0, 0);

#pragma unroll
        for (int r = 0; r < 4; ++r) {
            float ryv = QrY[wv][quad * 4 + r][jt + rybase[r]];
            float p0 = __expf(s0[r] + rx0[r] + ryv);
            float p1 = __expf(s1[r] + rx1[r] + ryv);
            lsum[r] += p0 + p1;
            Pb[wv][quad * 4 + r][n16]      = __float2bfloat16(p0);
            Pb[wv][quad * 4 + r][n16 + 16] = __float2bfloat16(p1);
        }
        s8v pA = *reinterpret_cast<const s8v*>(&Pb[wv][n16][quad * 8]);
        O0 = __builtin_amdgcn_mfma_f32_16x16x32_bf16(pA, cbv0, O0, 0, 0, 0);
        O1 = __builtin_amdgcn_mfma_f32_16x16x32_bf16(pA, cbv1, O1, 0, 0, 0);
    }

    const int b = bh >> 3, h = bh & 7;
#pragma unroll
    for (int r = 0; r < 4; ++r) {
        float l = lsum[r];
        l += __shfl_xor(l, 1);
        l += __shfl_xor(l, 2);
        l += __shfl_xor(l, 4);
        l += __shfl_xor(l, 8);
        float inv = 1.0f / l;
        int i = i0 + quad * 4 + r;
        int yi = i >> 5, xi = i & 31;
        __hip_bfloat16* op = attc + ((size_t)(b * 256 + h * 32 + yi) * 32 + xi) * 32;
        op[n16] = __float2bfloat16(O0[r] * inv);
        op[n16 + 16] = __float2bfloat16(O1[r] * inv);
    }
}

// ---------------- K3: 1x1 conv MFMA GEMM with fused transpose staging -------
__global__ __launch_bounds__(256) void conv1x1_gemm(
    const __hip_bfloat16* __restrict__ Wab, const __hip_bfloat16* __restrict__ attc,
    const float* __restrict__ att_b, float* __restrict__ out)
{
    __shared__ __align__(16) __hip_bfloat16 Ls[64][264];

    const int tid = threadIdx.x;
    const int wv = tid >> 6;
    const int lane = tid & 63;
    const int n16 = lane & 15;
    const int quad = lane >> 4;
    const int o0 = blockIdx.x * 64;
    const int p0 = blockIdx.y * 64;
    const int b = blockIdx.z;
    const int oW = o0 + (wv >> 1) * 32;
    const int pL = (wv & 1) * 32;

#pragma unroll
    for (int pass = 0; pass < 8; ++pass) {
        int ch = pass * 32 + (tid >> 3);
        int pg = (tid & 7) * 8;
        s8v v = *reinterpret_cast<const s8v*>(
            attc + ((size_t)(b * 256 + ch) * HWP) + p0 + pg);
#pragma unroll
        for (int j = 0; j < 8; ++j)
            Ls[pg + j][ch] = ((const __hip_bfloat16*)&v)[j];
    }
    __syncthreads();

    f32x4 acc[2][2];
#pragma unroll
    for (int i = 0; i < 2; ++i)
#pragma unroll
        for (int j = 0; j < 2; ++j) acc[i][j] = (f32x4){0.f, 0.f, 0.f, 0.f};

#pragma unroll
    for (int ks = 0; ks < 8; ++ks) {
        const int c0 = ks * 32 + quad * 8;
        s8v a0 = *reinterpret_cast<const s8v*>(Wab + (size_t)(oW + n16) * 256 + c0);
        s8v a1 = *reinterpret_cast<const s8v*>(Wab + (size_t)(oW + 16 + n16) * 256 + c0);
        s8v b0 = *reinterpret_cast<const s8v*>(&Ls[pL + n16][c0]);
        s8v b1 = *reinterpret_cast<const s8v*>(&Ls[pL + 16 + n16][c0]);
        acc[0][0] = __builtin_amdgcn_mfma_f32_16x16x32_bf16(a0, b0, acc[0][0], 0, 0, 0);
        acc[0][1] = __builtin_amdgcn_mfma_f32_16x16x32_bf16(a0, b1, acc[0][1], 0, 0, 0);
        acc[1][0] = __builtin_amdgcn_mfma_f32_16x16x32_bf16(a1, b0, acc[1][0], 0, 0, 0);
        acc[1][1] = __builtin_amdgcn_mfma_f32_16x16x32_bf16(a1, b1, acc[1][1], 0, 0, 0);
    }

#pragma unroll
    for (int mt = 0; mt < 2; ++mt)
#pragma unroll
        for (int r = 0; r < 4; ++r) {
            int o = oW + mt * 16 + quad * 4 + r;
            float bias = att_b[o];
            float* op = out + ((size_t)(b * 512 + 256 + o)) * HWP;
#pragma unroll
            for (int nt = 0; nt < 2; ++nt)
                op[p0 + pL + nt * 16 + n16] = acc[mt][nt][r] + bias;
        }
}

extern "C" void kernel_launch(void* const* d_in, const int* in_sizes, int n_in,
                              void* d_out, int out_size, void* d_ws, size_t ws_size,
                              hipStream_t stream) {
    const float* x      = (const float*)d_in[0];
    const float* conv_w = (const float*)d_in[1];
    const float* conv_b = (const float*)d_in[2];
    const float* qkv_w  = (const float*)d_in[3];
    const float* qkv_b  = (const float*)d_in[4];
    const float* att_w  = (const float*)d_in[5];
    const float* att_b  = (const float*)d_in[6];
    const float* kr_x   = (const float*)d_in[7];
    const float* kr_y   = (const float*)d_in[8];
    float* out = (float*)d_out;

    char* base = (char*)d_ws;
    const size_t MB = 1u << 20;
    __hip_bfloat16* qbf  = (__hip_bfloat16*)(base + 0 * MB);
    __hip_bfloat16* kbf  = (__hip_bfloat16*)(base + 2 * MB);
    __hip_bfloat16* vtb  = (__hip_bfloat16*)(base + 4 * MB);
    __hip_bfloat16* xT   = (__hip_bfloat16*)(base + 6 * MB);
    __hip_bfloat16* Wb   = (__hip_bfloat16*)(base + 8 * MB);
    __hip_bfloat16* attc = (__hip_bfloat16*)(base + 11 * MB);
    __hip_bfloat16* Wab  = (__hip_bfloat16*)(base + 13 * MB);
    __hip_bfloat16* krb  = (__hip_bfloat16*)(base + 14 * MB);

    prep_all<<<dim3(329), 256, 0, stream>>>(
        x, conv_w, qkv_w, att_w, kr_x, kr_y, xT, Wb, Wab, krb);
    conv_gemm<<<dim3(512), 256, 0, stream>>>(
        Wb, xT, conv_b, qkv_b, out, qbf, kbf, vtb);
    attn_kernel<<<dim3(32, 16), 256, 0, stream>>>(qbf, kbf, vtb, krb, attc);
    conv1x1_gemm<<<dim3(4, 16, 4), 256, 0, stream>>>(Wab, attc, att_b, out);
}